// Round 13
// baseline (306.359 us; speedup 1.0000x reference)
//
#include <hip/hip_runtime.h>
#include <cstdint>

#define NNODES 100000
#define NEDGES 1600000
#define NBKT   196          // ceil(NNODES / 512); bucket = dst >> 9
#define CAP    9216         // per-bucket capacity: mean 8192 + ~11 sigma
#define BIN_CHUNK 4096
#define GBIN ((NEDGES + BIN_CHUNK - 1) / BIN_CHUNK)   // 391
#define GCVT (NNODES * 16 / 256)                      // 6250 (1 uint4/thread)
#define GWPK 24                                       // weight-pack blocks (6144 thr)

typedef __attribute__((ext_vector_type(8))) __bf16 bf16x8;
typedef __attribute__((ext_vector_type(4))) float f32x4;
typedef short v2s __attribute__((ext_vector_type(2)));

__device__ __forceinline__ unsigned short f2bf_rne(float f) {
    unsigned int u = __float_as_uint(f);
    u += 0x7fffu + ((u >> 16) & 1u);
    return (unsigned short)(u >> 16);
}
// involutive monotone map: bf16 float order <-> signed i16 order (per packed half)
__device__ __forceinline__ unsigned encdec(unsigned u) {
    return u ^ (((u & 0x80008000u) >> 15) * 0x7FFFu);
}
__device__ __forceinline__ unsigned pkmax(unsigned a, unsigned b) {
    v2s r = __builtin_elementwise_max(__builtin_bit_cast(v2s, a), __builtin_bit_cast(v2s, b));
    return __builtin_bit_cast(unsigned, r);
}
__device__ __forceinline__ uint4 pkmax4(uint4 a, uint4 b) {
    uint4 r;
    r.x = pkmax(a.x, b.x); r.y = pkmax(a.y, b.y);
    r.z = pkmax(a.z, b.z); r.w = pkmax(a.w, b.w);
    return r;
}
__device__ __forceinline__ uint4 dec4(uint4 a) {
    uint4 r;
    r.x = encdec(a.x); r.y = encdec(a.y); r.z = encdec(a.z); r.w = encdec(a.w);
    return r;
}

// ===== 2-SLICE layout =====
// Feature matrices [N][128] bf16 stored as 2 slices of 64 channels:
//   uint4 index(slice s, node n, j) = ((size_t)s*N + n)*8 + j,  j in [0,8)
// Global uint4 q = s*8+j holds channels q*8..q*8+7.

// ---------------- prep: bin edges | encode x | pack weights (R9-proven) ------
__global__ __launch_bounds__(256) void prep_kernel(
        const int* __restrict__ src, const int* __restrict__ dst,
        unsigned int* __restrict__ binArr, int* __restrict__ bucketFill,
        const float4* __restrict__ xin, uint4* __restrict__ xeout,
        const float* __restrict__ W1l, const float* __restrict__ W1r,
        const float* __restrict__ W2l, const float* __restrict__ W2r,
        uint4* __restrict__ Wf1, uint4* __restrict__ Wf2, int nE) {
    if (blockIdx.x >= GBIN + GCVT) {
        int t = (blockIdx.x - GBIN - GCVT) * 256 + threadIdx.x;   // 0..6143
        unsigned short s[8];
        if (t < 4096) {                           // layer 1: BN=128, NT=8
            int h = t >> 11, kt = (t >> 9) & 3, nt = (t >> 6) & 7, lane = t & 63;
            const float* W = h ? W1r : W1l;
            int k0 = kt * 32 + (lane >> 4) * 8;
            int col = nt * 16 + (lane & 15);
#pragma unroll
            for (int jj = 0; jj < 8; ++jj) s[jj] = f2bf_rne(W[(k0 + jj) * 128 + col]);
            uint4 o;
            o.x = (unsigned)s[0] | ((unsigned)s[1] << 16);
            o.y = (unsigned)s[2] | ((unsigned)s[3] << 16);
            o.z = (unsigned)s[4] | ((unsigned)s[5] << 16);
            o.w = (unsigned)s[6] | ((unsigned)s[7] << 16);
            Wf1[t] = o;
        } else {                                  // layer 2: BN=64, NT=4
            int u = t - 4096;                     // 0..2047
            int h = u >> 10, kt = (u >> 8) & 3, nt = (u >> 6) & 3, lane = u & 63;
            const float* W = h ? W2r : W2l;
            int k0 = kt * 32 + (lane >> 4) * 8;
            int col = nt * 16 + (lane & 15);
#pragma unroll
            for (int jj = 0; jj < 8; ++jj) s[jj] = f2bf_rne(W[(k0 + jj) * 64 + col]);
            uint4 o;
            o.x = (unsigned)s[0] | ((unsigned)s[1] << 16);
            o.y = (unsigned)s[2] | ((unsigned)s[3] << 16);
            o.z = (unsigned)s[4] | ((unsigned)s[5] << 16);
            o.w = (unsigned)s[6] | ((unsigned)s[7] << 16);
            Wf2[u] = o;
        }
        return;
    }
    if (blockIdx.x >= GBIN) {
        // ---- encode x into sliced layout ----
        int t = (blockIdx.x - GBIN) * 256 + threadIdx.x;  // 0..1.6M-1 sliced uint4 idx
        int s = t / (NNODES * 8);
        int rem = t - s * (NNODES * 8);
        int n = rem >> 3, j = rem & 7;
        int f = n * 32 + s * 16 + j * 2;                  // float4 idx (ch 64s+8j)
        float4 v0 = xin[f], v1 = xin[f + 1];
        uint4 o;
        o.x = encdec((unsigned)f2bf_rne(v0.x) | ((unsigned)f2bf_rne(v0.y) << 16));
        o.y = encdec((unsigned)f2bf_rne(v0.z) | ((unsigned)f2bf_rne(v0.w) << 16));
        o.z = encdec((unsigned)f2bf_rne(v1.x) | ((unsigned)f2bf_rne(v1.y) << 16));
        o.w = encdec((unsigned)f2bf_rne(v1.z) | ((unsigned)f2bf_rne(v1.w) << 16));
        xeout[t] = o;
        return;
    }
    // ---- bin: entry = (dst&511)<<17 | src; pass-1 ordinal makes pass-2 atomic-free
    __shared__ unsigned int stage[BIN_CHUNK];
    __shared__ unsigned char bof[BIN_CHUNK];
    __shared__ int cnt[256], cstart[256], gbase[256];
    const int tid = threadIdx.x;
    const int blockStart = blockIdx.x * BIN_CHUNK;
    const int chunkN = min(BIN_CHUNK, nE - blockStart);
    cnt[tid] = 0;
    __syncthreads();
    int myd[16], mys[16];
    unsigned short myo[16];
#pragma unroll
    for (int i = 0; i < 16; ++i) {
        int idx = i * 256 + tid;
        if (idx < chunkN) {
            myd[i] = dst[blockStart + idx];
            mys[i] = src[blockStart + idx];
            myo[i] = (unsigned short)atomicAdd(&cnt[myd[i] >> 9], 1);
        }
    }
    __syncthreads();
    int v = cnt[tid];
    for (int off = 1; off < 256; off <<= 1) {
        int add = (tid >= off) ? cnt[tid - off] : 0;
        __syncthreads();
        cnt[tid] += add;
        __syncthreads();
    }
    cstart[tid] = cnt[tid] - v;
    if (tid < NBKT && v > 0) gbase[tid] = atomicAdd(&bucketFill[tid], v);
    __syncthreads();
#pragma unroll
    for (int i = 0; i < 16; ++i) {
        int idx = i * 256 + tid;
        if (idx < chunkN) {
            int b = myd[i] >> 9;
            int p = cstart[b] + (int)myo[i];              // atomic-free placement
            stage[p] = ((unsigned)(myd[i] & 511) << 17) | (unsigned)mys[i];
            bof[p] = (unsigned char)b;
        }
    }
    __syncthreads();
#pragma unroll
    for (int i = 0; i < 16; ++i) {
        int idx = i * 256 + tid;
        if (idx < chunkN) {
            int b = bof[idx];
            int slot = gbase[b] + (idx - cstart[b]);
            if (slot < CAP) binArr[(size_t)b * CAP + slot] = stage[idx];
        }
    }
}

// ---------------- per-bucket CSR build, 1024 threads, atomic-free scatter ----
__global__ __launch_bounds__(1024) void build_csr_kernel(
        const unsigned int* __restrict__ binArr, const int* __restrict__ bucketFill,
        unsigned int* __restrict__ sortedSrc,
        int* __restrict__ rowBeg, int* __restrict__ rowEnd) {
    __shared__ unsigned int stage[CAP];
    __shared__ unsigned short ordv[CAP];
    __shared__ int ncnt[512], nstart[512];
    const int b = blockIdx.x;
    const int t = threadIdx.x;
    const int cnt_b = min(bucketFill[b], CAP);
    if (t < 512) ncnt[t] = 0;
    __syncthreads();
    for (int i = t; i < cnt_b; i += 1024) {
        unsigned int e = binArr[(size_t)b * CAP + i];
        stage[i] = e;
        ordv[i] = (unsigned short)atomicAdd(&ncnt[e >> 17], 1);  // ordinal captured
    }
    __syncthreads();
    int v = (t < 512) ? ncnt[t] : 0;
    for (int off = 1; off < 512; off <<= 1) {
        int add = (t >= off && t < 512) ? ncnt[t - off] : 0;
        __syncthreads();
        if (t < 512) ncnt[t] += add;
        __syncthreads();
    }
    if (t < 512) {
        int start = ncnt[t] - v;
        nstart[t] = start;
        int n = (b << 9) + t;
        if (n < NNODES) {
            rowBeg[n] = b * CAP + start;
            rowEnd[n] = b * CAP + start + v;
        }
    }
    __syncthreads();
    for (int i = t; i < cnt_b; i += 1024) {
        unsigned int e = stage[i];
        sortedSrc[(size_t)b * CAP + nstart[e >> 17] + (int)ordv[i]] = e & 0x1FFFFu;
    }
}

// ---------------- BARRIER-FREE fused aggregate + GEMM -----------------------
// Wave owns 16 nodes x 128 channels. Lane = fq(2b)<<4 | nd(4b).
// acc[kt] (uint4) = channels (kt*4+fq)*8..+7 of node nd -- this IS the MFMA
// A-fragment layout (row=lane&15, k=(lane>>4)*8+j). Gather -> pkmax -> MFMA
// entirely in registers: no LDS, no barriers, no wave convoy.
template<int BN, bool RELU, bool ENCOUT, typename OutT>
__global__ __launch_bounds__(256) void sage_fused_bf(
        const uint4* __restrict__ xsl,          // sliced encoded features
        const int* __restrict__ rowBeg,
        const int* __restrict__ rowEnd,
        const unsigned int* __restrict__ sortedSrc,
        const uint4* __restrict__ Wf,           // fragment-packed weights
        const float* __restrict__ bias,         // [BN] f32
        OutT* __restrict__ C,                   // ENCOUT: sliced bf16; else [M][BN] f32
        int nN) {
    constexpr int NT = BN / 16;                 // column tiles (8 or 4)
    const int wv   = threadIdx.x >> 6;
    const int lane = threadIdx.x & 63;
    const int nd   = lane & 15;                 // node within wave
    const int fq   = lane >> 4;                 // fragment quad 0..3
    const int nbase = blockIdx.x * 64 + wv * 16;
    if (nbase >= nN) return;                    // whole-wave OOB (no barriers -> safe)

    const int n = min(nbase + nd, nN - 1);
    const int beg = rowBeg[n], end = rowEnd[n];
    const int m = end - beg;

    // wave-max degree over the nd dimension (m independent of fq)
    int maxm = m;
    maxm = max(maxm, __shfl_xor(maxm, 1));
    maxm = max(maxm, __shfl_xor(maxm, 2));
    maxm = max(maxm, __shfl_xor(maxm, 4));
    maxm = max(maxm, __shfl_xor(maxm, 8));

    // per-kt uint4 base offsets: q = kt*4+fq -> addr(id) = c[kt] + id*8
    const size_t c0 = (size_t)fq;                        // q=fq      (s0, j=fq)
    const size_t c1 = (size_t)(4 + fq);                  // q=4+fq    (s0, j=4+fq)
    const size_t c2 = (size_t)nN * 8 + fq;               // q=8+fq    (s1, j=fq)
    const size_t c3 = (size_t)nN * 8 + 4 + fq;           // q=12+fq   (s1, j=4+fq)

    // prologue ids: 16 edges (clamp-duplicated), lane fq holds edge 4b+fq
    int idv0 = 0, idv1 = 0, idv2 = 0, idv3 = 0;
    if (m > 0) {
        idv0 = (int)sortedSrc[min(beg + 0  + fq, end - 1)];
        idv1 = (int)sortedSrc[min(beg + 4  + fq, end - 1)];
        idv2 = (int)sortedSrc[min(beg + 8  + fq, end - 1)];
        idv3 = (int)sortedSrc[min(beg + 12 + fq, end - 1)];
    }

    uint4 acc0, acc1, acc2, acc3;
    {   // batch 0 (init)
        int e0 = __shfl(idv0, nd), e1 = __shfl(idv0, 16 + nd);
        int e2 = __shfl(idv0, 32 + nd), e3 = __shfl(idv0, 48 + nd);
        uint4 p00 = xsl[c0 + (size_t)e0 * 8], p10 = xsl[c0 + (size_t)e1 * 8];
        uint4 p20 = xsl[c0 + (size_t)e2 * 8], p30 = xsl[c0 + (size_t)e3 * 8];
        uint4 p01 = xsl[c1 + (size_t)e0 * 8], p11 = xsl[c1 + (size_t)e1 * 8];
        uint4 p21 = xsl[c1 + (size_t)e2 * 8], p31 = xsl[c1 + (size_t)e3 * 8];
        uint4 p02 = xsl[c2 + (size_t)e0 * 8], p12 = xsl[c2 + (size_t)e1 * 8];
        uint4 p22 = xsl[c2 + (size_t)e2 * 8], p32 = xsl[c2 + (size_t)e3 * 8];
        uint4 p03 = xsl[c3 + (size_t)e0 * 8], p13 = xsl[c3 + (size_t)e1 * 8];
        uint4 p23 = xsl[c3 + (size_t)e2 * 8], p33 = xsl[c3 + (size_t)e3 * 8];
        acc0 = pkmax4(pkmax4(p00, p10), pkmax4(p20, p30));
        acc1 = pkmax4(pkmax4(p01, p11), pkmax4(p21, p31));
        acc2 = pkmax4(pkmax4(p02, p12), pkmax4(p22, p32));
        acc3 = pkmax4(pkmax4(p03, p13), pkmax4(p23, p33));
    }
#define BATCH_ACC(idv)                                                         \
    {                                                                          \
        int e0 = __shfl(idv, nd), e1 = __shfl(idv, 16 + nd);                   \
        int e2 = __shfl(idv, 32 + nd), e3 = __shfl(idv, 48 + nd);              \
        uint4 p00 = xsl[c0 + (size_t)e0 * 8], p10 = xsl[c0 + (size_t)e1 * 8];  \
        uint4 p20 = xsl[c0 + (size_t)e2 * 8], p30 = xsl[c0 + (size_t)e3 * 8];  \
        uint4 p01 = xsl[c1 + (size_t)e0 * 8], p11 = xsl[c1 + (size_t)e1 * 8];  \
        uint4 p21 = xsl[c1 + (size_t)e2 * 8], p31 = xsl[c1 + (size_t)e3 * 8];  \
        uint4 p02 = xsl[c2 + (size_t)e0 * 8], p12 = xsl[c2 + (size_t)e1 * 8];  \
        uint4 p22 = xsl[c2 + (size_t)e2 * 8], p32 = xsl[c2 + (size_t)e3 * 8];  \
        uint4 p03 = xsl[c3 + (size_t)e0 * 8], p13 = xsl[c3 + (size_t)e1 * 8];  \
        uint4 p23 = xsl[c3 + (size_t)e2 * 8], p33 = xsl[c3 + (size_t)e3 * 8];  \
        acc0 = pkmax4(acc0, pkmax4(pkmax4(p00, p10), pkmax4(p20, p30)));       \
        acc1 = pkmax4(acc1, pkmax4(pkmax4(p01, p11), pkmax4(p21, p31)));       \
        acc2 = pkmax4(acc2, pkmax4(pkmax4(p02, p12), pkmax4(p22, p32)));       \
        acc3 = pkmax4(acc3, pkmax4(pkmax4(p03, p13), pkmax4(p23, p33)));       \
    }
    BATCH_ACC(idv1);
    BATCH_ACC(idv2);
    BATCH_ACC(idv3);

    // masked tail: 4 edges per round, per-node-group predicate (uniform in fq)
    for (int eb = 16; eb < maxm; eb += 4) {
        if (eb < m) {
            int idt = (int)sortedSrc[min(beg + eb + fq, end - 1)];
            BATCH_ACC(idt);
        }
    }
#undef BATCH_ACC

    // isolated nodes -> aggr = 0 (enc(0)==0)
    if (m == 0) {
        acc0 = (uint4){0, 0, 0, 0}; acc1 = acc0; acc2 = acc0; acc3 = acc0;
    }

    // root fragments (same A-frag layout, row n)
    uint4 tr0 = xsl[c0 + (size_t)n * 8];
    uint4 tr1 = xsl[c1 + (size_t)n * 8];
    uint4 tr2 = xsl[c2 + (size_t)n * 8];
    uint4 tr3 = xsl[c3 + (size_t)n * 8];

    bf16x8 aa0 = __builtin_bit_cast(bf16x8, dec4(acc0));
    bf16x8 aa1 = __builtin_bit_cast(bf16x8, dec4(acc1));
    bf16x8 aa2 = __builtin_bit_cast(bf16x8, dec4(acc2));
    bf16x8 aa3 = __builtin_bit_cast(bf16x8, dec4(acc3));
    bf16x8 ar0 = __builtin_bit_cast(bf16x8, dec4(tr0));
    bf16x8 ar1 = __builtin_bit_cast(bf16x8, dec4(tr1));
    bf16x8 ar2 = __builtin_bit_cast(bf16x8, dec4(tr2));
    bf16x8 ar3 = __builtin_bit_cast(bf16x8, dec4(tr3));

    // GEMM: 16 rows x BN, 8 MFMAs per column tile
#pragma unroll
    for (int nt = 0; nt < NT; ++nt) {
        f32x4 cacc = (f32x4){0.f, 0.f, 0.f, 0.f};
        cacc = __builtin_amdgcn_mfma_f32_16x16x32_bf16(
            aa0, __builtin_bit_cast(bf16x8, Wf[(0 * NT + nt) * 64 + lane]), cacc, 0, 0, 0);
        cacc = __builtin_amdgcn_mfma_f32_16x16x32_bf16(
            aa1, __builtin_bit_cast(bf16x8, Wf[(1 * NT + nt) * 64 + lane]), cacc, 0, 0, 0);
        cacc = __builtin_amdgcn_mfma_f32_16x16x32_bf16(
            aa2, __builtin_bit_cast(bf16x8, Wf[(2 * NT + nt) * 64 + lane]), cacc, 0, 0, 0);
        cacc = __builtin_amdgcn_mfma_f32_16x16x32_bf16(
            aa3, __builtin_bit_cast(bf16x8, Wf[(3 * NT + nt) * 64 + lane]), cacc, 0, 0, 0);
        cacc = __builtin_amdgcn_mfma_f32_16x16x32_bf16(
            ar0, __builtin_bit_cast(bf16x8, Wf[(4 * NT + nt) * 64 + lane]), cacc, 0, 0, 0);
        cacc = __builtin_amdgcn_mfma_f32_16x16x32_bf16(
            ar1, __builtin_bit_cast(bf16x8, Wf[(5 * NT + nt) * 64 + lane]), cacc, 0, 0, 0);
        cacc = __builtin_amdgcn_mfma_f32_16x16x32_bf16(
            ar2, __builtin_bit_cast(bf16x8, Wf[(6 * NT + nt) * 64 + lane]), cacc, 0, 0, 0);
        cacc = __builtin_amdgcn_mfma_f32_16x16x32_bf16(
            ar3, __builtin_bit_cast(bf16x8, Wf[(7 * NT + nt) * 64 + lane]), cacc, 0, 0, 0);

        // epilogue: D layout col=lane&15 (=nd), row=fq*4+reg
        const int col = nt * 16 + nd;
        const float bv = bias[col];
#pragma unroll
        for (int rr = 0; rr < 4; ++rr) {
            const int grow = nbase + fq * 4 + rr;
            if (grow < nN) {
                float vv = cacc[rr] + bv;
                if (RELU) vv = fmaxf(vv, 0.0f);
                if constexpr (ENCOUT) {
                    unsigned u = f2bf_rne(vv);
                    u ^= ((u >> 15) & 1u) * 0x7FFFu;   // encode for next layer
                    C[((size_t)(col >> 6) * nN + grow) * 64 + (col & 63)] = (OutT)u;
                } else {
                    C[(size_t)grow * BN + col] = (OutT)vv;
                }
            }
        }
    }
}

extern "C" void kernel_launch(void* const* d_in, const int* in_sizes, int n_in,
                              void* d_out, int out_size, void* d_ws, size_t ws_size,
                              hipStream_t stream) {
    const float* x   = (const float*)d_in[0];
    const int*   ei  = (const int*)d_in[1];
    const float* W1l = (const float*)d_in[2];
    const float* b1l = (const float*)d_in[3];
    const float* W1r = (const float*)d_in[4];
    const float* W2l = (const float*)d_in[5];
    const float* b2l = (const float*)d_in[6];
    const float* W2r = (const float*)d_in[7];
    float* out = (float*)d_out;

    const int* src = ei;
    const int* dst = ei + NEDGES;

    // ---- workspace layout ----
    char* ws = (char*)d_ws;
    unsigned short* xe    = (unsigned short*)ws; ws += (size_t)NNODES * 128 * 2;  // 25.6 MB sliced
    unsigned short* he    = (unsigned short*)ws; ws += (size_t)NNODES * 128 * 2;  // 25.6 MB sliced
    unsigned int* binArr    = (unsigned int*)ws; ws += (size_t)NBKT * CAP * 4;    // 7.2 MB
    unsigned int* sortedSrc = (unsigned int*)ws; ws += (size_t)NBKT * CAP * 4;    // 7.2 MB
    int* rowBeg     = (int*)ws; ws += (size_t)NNODES * 4;
    int* rowEnd     = (int*)ws; ws += (size_t)NNODES * 4;
    int* bucketFill = (int*)ws; ws += 256 * 4;
    uint4* Wf1 = (uint4*)ws; ws += 4096 * 16;   // 64 KB fragment-packed L1 weights
    uint4* Wf2 = (uint4*)ws; ws += 2048 * 16;   // 32 KB fragment-packed L2 weights

    const int gFus = (NNODES + 63) / 64;        // 1563 blocks x 64 nodes

    hipMemsetAsync(bucketFill, 0, 256 * sizeof(int), stream);
    prep_kernel<<<GBIN + GCVT + GWPK, 256, 0, stream>>>(
        src, dst, binArr, bucketFill, (const float4*)x, (uint4*)xe,
        W1l, W1r, W2l, W2r, Wf1, Wf2, NEDGES);
    build_csr_kernel<<<NBKT, 1024, 0, stream>>>(binArr, bucketFill, sortedSrc, rowBeg, rowEnd);

    // ---- layer 1: aggregate(xe) + GEMM -> he (sliced, encoded, relu) ----
    sage_fused_bf<128, true, true, unsigned short><<<gFus, 256, 0, stream>>>(
        (const uint4*)xe, rowBeg, rowEnd, sortedSrc, Wf1, b1l, he, NNODES);
    // ---- layer 2: aggregate(he) + GEMM -> out (linear f32) ----
    sage_fused_bf<64, false, false, float><<<gFus, 256, 0, stream>>>(
        (const uint4*)he, rowBeg, rowEnd, sortedSrc, Wf2, b2l, out, NNODES);
}